// Round 5
// baseline (8559.863 us; speedup 1.0000x reference)
//
#include <hip/hip_runtime.h>

// DecoderWithAttention: B=16, T=32, F=8, S_ENC=256, H=512, L=2.
// R11: zero-communication main loop (theory: the 4 serialized system-scope
// round trips/step (~5-6us each at the MALL) are irreducible by topology --
// so remove cross-block comm entirely).
//  - Kernel 1 (256x256): f16 weight packing (no internal sync needed).
//  - Kernel 2 (256x256): enc_proj (reads packed aehU; kernel boundary = free
//    global barrier + cache coherence).
//  - Main kernel (16 blocks x 1024 threads): one block per batch. The whole
//    32-step recurrence runs on one CU; all phase hand-offs are __syncthreads.
//    No atomics, no system-scope ops, no tags, no memset.
//  - Weights stream from L2/MALL each step (~7MB/step/block, 2 blocks/XCD
//    share the same addresses). Biases/v_w pinned in LDS (~53KB total).

namespace {
constexpr int NTHR_P = 256;   // prologue kernels
constexpr int NBLK_P = 256;
constexpr int NTHR_M = 1024;  // main kernel
constexpr int NBLK_M = 16;

// ws float offsets (u32 payloads; no counters/tags needed).
constexpr int OFF_AEH   = 0;                      // [512][256] u32 attn_W[:,512:]
constexpr int OFF_WHID  = OFF_AEH + 131072;       // [512][256] u32 attn_W[:,:512]
constexpr int OFF_WIH0  = OFF_WHID + 131072;      // [1536][260] u32
constexpr int OFF_WHH0  = OFF_WIH0 + 399360;      // [1536][256] u32
constexpr int OFF_WIH1  = OFF_WHH0 + 393216;      // [1536][256] u32
constexpr int OFF_WHH1  = OFF_WIH1 + 393216;      // [1536][256] u32
constexpr int OFF_ENCP  = OFF_WHH1 + 393216;      // [4096][256] u32 enc_proj f16
// end = 2,889,728 floats = 11.56 MB

// Main-kernel LDS float/u32 offsets (total 13356 floats = 53.4 KB)
constexpr int L_H0   = 0;      // [256] u32 h0 f16x2
constexpr int L_H1   = 256;    // [256] u32 h1 f16x2
constexpr int L_HIDP = 512;    // [512] f32
constexpr int L_ES   = 1024;   // [256] f32 exp(score)
constexpr int L_HX   = 1280;   // [264] u32: xin(4) | weighted(256) | pad(4)
constexpr int L_AX   = 1544;   // [1536] f32
constexpr int L_AH   = 3080;   // [1536] f32
constexpr int L_WS4  = 4616;   // [4][512] f32 weighted partials
constexpr int L_VW   = 6664;   // [512] f32
constexpr int L_XIN  = 7176;   // [8] f32
constexpr int L_INV  = 7184;   // [1] f32
constexpr int L_OUTR = 7188;   // [16] f32 per-wave out partials
constexpr int L_BIH0 = 7204;   // [1536]
constexpr int L_BHH0 = 8740;   // [1536]
constexpr int L_BIH1 = 10276;  // [1536]
constexpr int L_BHH1 = 11812;  // [1536]
constexpr int L_OB   = 13348;  // [8]
constexpr int LDS_M  = 13356;
}  // namespace

typedef _Float16 h2 __attribute__((ext_vector_type(2)));
union U32H { unsigned u; h2 h; };

__device__ __forceinline__ float dot2(unsigned a, unsigned b, float acc) {
    U32H ua, ub; ua.u = a; ub.u = b;
#if __has_builtin(__builtin_amdgcn_fdot2)
    return __builtin_amdgcn_fdot2(ua.h, ub.h, acc, false);
#else
    return acc + (float)ua.h.x * (float)ub.h.x + (float)ua.h.y * (float)ub.h.y;
#endif
}
__device__ __forceinline__ unsigned packh2(float a, float b) {
    U32H u; u.h = h2{(_Float16)a, (_Float16)b}; return u.u;
}
__device__ __forceinline__ float fsig(float x) { return 1.0f / (1.0f + __expf(-x)); }
__device__ __forceinline__ float ftanhf(float x) {
    float e = __expf(2.0f * x);
    return 1.0f - 2.0f / (e + 1.0f);
}

// ===================== Kernel 1: f16 weight packing =====================
__global__ __launch_bounds__(NTHR_P) void pack_kernel(
    const float* __restrict__ attn_W, const float* __restrict__ Wih0,
    const float* __restrict__ Whh0, const float* __restrict__ Wih1,
    const float* __restrict__ Whh1, float* __restrict__ ws) {
    unsigned* aehU  = (unsigned*)(ws + OFF_AEH);
    unsigned* whidU = (unsigned*)(ws + OFF_WHID);
    unsigned* wih0U = (unsigned*)(ws + OFF_WIH0);
    unsigned* whh0U = (unsigned*)(ws + OFF_WHH0);
    unsigned* wih1U = (unsigned*)(ws + OFF_WIH1);
    unsigned* whh1U = (unsigned*)(ws + OFF_WHH1);
    const int gtid = blockIdx.x * NTHR_P + threadIdx.x;
    for (int i = gtid; i < 131072; i += NBLK_P * NTHR_P) {
        const int jr = i >> 8, p = i & 255;
        aehU[i]  = packh2(attn_W[jr * 1024 + 512 + 2 * p], attn_W[jr * 1024 + 513 + 2 * p]);
        whidU[i] = packh2(attn_W[jr * 1024 + 2 * p], attn_W[jr * 1024 + 1 + 2 * p]);
    }
    for (int i = gtid; i < 399360; i += NBLK_P * NTHR_P)
        wih0U[i] = packh2(Wih0[2 * i], Wih0[2 * i + 1]);
    for (int i = gtid; i < 393216; i += NBLK_P * NTHR_P) {
        whh0U[i] = packh2(Whh0[2 * i], Whh0[2 * i + 1]);
        wih1U[i] = packh2(Wih1[2 * i], Wih1[2 * i + 1]);
        whh1U[i] = packh2(Whh1[2 * i], Whh1[2 * i + 1]);
    }
}

// ===================== Kernel 2: enc_proj =====================
__global__ __launch_bounds__(NTHR_P) void encp_kernel(
    const float* __restrict__ enc, const float* __restrict__ attn_b,
    float* __restrict__ ws) {
    const int tid = threadIdx.x, bid = blockIdx.x;
    const int b = bid >> 4, s = bid & 15;
    const unsigned* aehU = (const unsigned*)(ws + OFF_AEH);
    unsigned* encpU = (unsigned*)(ws + OFF_ENCP);
    __shared__ __align__(16) float lds[8192];
    for (int i = 0; i < 32; ++i) {
        const int idx = tid + i * 256;
        lds[idx] = enc[(b * 256 + s * 16) * 512 + idx];  // 16 s x 512
    }
    __syncthreads();
    float a0[16], a1[16];
    const float bb0 = attn_b[2 * tid], bb1 = attn_b[2 * tid + 1];
#pragma unroll
    for (int sl = 0; sl < 16; ++sl) { a0[sl] = bb0; a1[sl] = bb1; }
    const unsigned* w0 = &aehU[(2 * tid) * 256];
    const unsigned* w1 = &aehU[(2 * tid + 1) * 256];
    for (int p = 0; p < 256; ++p) {
        const unsigned ww0 = w0[p], ww1 = w1[p];
#pragma unroll
        for (int sl = 0; sl < 16; ++sl) {
            const unsigned epk = packh2(lds[sl * 512 + 2 * p], lds[sl * 512 + 2 * p + 1]);
            a0[sl] = dot2(epk, ww0, a0[sl]);
            a1[sl] = dot2(epk, ww1, a1[sl]);
        }
    }
    for (int sl = 0; sl < 16; ++sl)
        encpU[(b * 256 + s * 16 + sl) * 256 + tid] = packh2(a0[sl], a1[sl]);
}

// ===================== Main kernel: 1 block per batch =====================
__global__ __launch_bounds__(NTHR_M) void decoder_kernel(
    const float* __restrict__ target, const float* __restrict__ hidden0,
    const float* __restrict__ enc, const float* __restrict__ v_w,
    const float* __restrict__ bih0, const float* __restrict__ bhh0,
    const float* __restrict__ bih1, const float* __restrict__ bhh1,
    const float* __restrict__ outW, const float* __restrict__ outBias,
    float* __restrict__ out, float* __restrict__ ws) {
    const int tid = threadIdx.x;
    const int b = blockIdx.x;

    const unsigned* whidU = (const unsigned*)(ws + OFF_WHID);
    const unsigned* wih0U = (const unsigned*)(ws + OFF_WIH0);
    const unsigned* whh0U = (const unsigned*)(ws + OFF_WHH0);
    const unsigned* wih1U = (const unsigned*)(ws + OFF_WIH1);
    const unsigned* whh1U = (const unsigned*)(ws + OFF_WHH1);
    const unsigned* encpU = (const unsigned*)(ws + OFF_ENCP);

    __shared__ __align__(16) float lds[LDS_M];
    unsigned* ldsU = (unsigned*)lds;

    // ---- init: pin biases/v_w/outBias, pack h0/h1, xin, pad ----
    for (int i = tid; i < 1536; i += NTHR_M) {
        lds[L_BIH0 + i] = bih0[i]; lds[L_BHH0 + i] = bhh0[i];
        lds[L_BIH1 + i] = bih1[i]; lds[L_BHH1 + i] = bhh1[i];
    }
    if (tid < 512) lds[L_VW + tid] = v_w[tid];
    if (tid < 256) {
        ldsU[L_H0 + tid] = packh2(hidden0[b * 512 + 2 * tid], hidden0[b * 512 + 2 * tid + 1]);
        ldsU[L_H1 + tid] = packh2(hidden0[8192 + b * 512 + 2 * tid],
                                  hidden0[8192 + b * 512 + 2 * tid + 1]);
    }
    if (tid < 8) { lds[L_XIN + tid] = target[b * 256 + tid]; lds[L_OB + tid] = outBias[tid]; }
    if (tid < 4) ldsU[L_HX + 260 + tid] = 0u;  // permanent zero tail pad
    __syncthreads();

    for (int t = 0; t < 32; ++t) {
        // ---- P0: hidP = whid @ h1 (512 rows, 2 thr/row) ----
        {
            const int row = tid >> 1, sub = tid & 1;
            const uint4* w = (const uint4*)&whidU[row * 256 + sub * 128];
            const uint4* h = (const uint4*)&ldsU[L_H1 + sub * 128];
            float a0 = 0.f, a1 = 0.f;
#pragma unroll 8
            for (int k = 0; k < 32; k += 2) {
                const uint4 h0v = h[k], w0v = w[k];
                a0 = dot2(h0v.x, w0v.x, a0); a0 = dot2(h0v.y, w0v.y, a0);
                a0 = dot2(h0v.z, w0v.z, a0); a0 = dot2(h0v.w, w0v.w, a0);
                const uint4 h1v = h[k + 1], w1v = w[k + 1];
                a1 = dot2(h1v.x, w1v.x, a1); a1 = dot2(h1v.y, w1v.y, a1);
                a1 = dot2(h1v.z, w1v.z, a1); a1 = dot2(h1v.w, w1v.w, a1);
            }
            float acc = a0 + a1;
            acc += __shfl_down(acc, 1, 2);
            if (sub == 0) lds[L_HIDP + row] = acc;
        }
        __syncthreads();

        // ---- P1a: scores (256 s-rows, 4 thr/row) + exp ----
        {
            const int srow = tid >> 2, sub = tid & 3;
            const unsigned* ep = &encpU[(b * 256 + srow) * 256 + sub * 64];
            float acc = 0.f;
#pragma unroll 8
            for (int k = 0; k < 64; ++k) {
                const int p = sub * 64 + k;
                U32H u; u.u = ep[k];
                acc += lds[L_VW + 2 * p] * ftanhf((float)u.h.x + lds[L_HIDP + 2 * p]);
                acc += lds[L_VW + 2 * p + 1] * ftanhf((float)u.h.y + lds[L_HIDP + 2 * p + 1]);
            }
            acc += __shfl_down(acc, 2, 4); acc += __shfl_down(acc, 1, 4);
            if (sub == 0) lds[L_ES + srow] = __expf(acc);  // |score|<=~20: fp32-safe
        }
        __syncthreads();

        // ---- P1b: weighted partials (4 s-subranges) + L ----
        {
            const int ppair = tid & 255, sg = tid >> 8;
            const float2* er = (const float2*)&enc[(b * 256 + sg * 64) * 512];
            float wp0 = 0.f, wp1 = 0.f;
#pragma unroll 8
            for (int sl = 0; sl < 64; ++sl) {
                const float2 e = er[sl * 256 + ppair];
                const float es = lds[L_ES + sg * 64 + sl];
                wp0 += es * e.x; wp1 += es * e.y;
            }
            lds[L_WS4 + sg * 512 + 2 * ppair] = wp0;
            lds[L_WS4 + sg * 512 + 2 * ppair + 1] = wp1;
        }
        if (tid < 64) {
            float l = lds[L_ES + tid] + lds[L_ES + 64 + tid] +
                      lds[L_ES + 128 + tid] + lds[L_ES + 192 + tid];
            l += __shfl_down(l, 32, 64); l += __shfl_down(l, 16, 64);
            l += __shfl_down(l, 8, 64); l += __shfl_down(l, 4, 64);
            l += __shfl_down(l, 2, 64); l += __shfl_down(l, 1, 64);
            if (tid == 0) lds[L_INV] = 1.f / l;
        }
        __syncthreads();
        if (tid < 256) {
            const float inv = lds[L_INV];
            const float w0 = (lds[L_WS4 + 2 * tid] + lds[L_WS4 + 512 + 2 * tid] +
                              lds[L_WS4 + 1024 + 2 * tid] + lds[L_WS4 + 1536 + 2 * tid]) * inv;
            const float w1 = (lds[L_WS4 + 2 * tid + 1] + lds[L_WS4 + 512 + 2 * tid + 1] +
                              lds[L_WS4 + 1024 + 2 * tid + 1] + lds[L_WS4 + 1536 + 2 * tid + 1]) * inv;
            ldsU[L_HX + 4 + tid] = packh2(w0, w1);
        }
        if (tid >= 256 && tid < 260) {
            const int q = tid - 256;
            ldsU[L_HX + q] = packh2(lds[L_XIN + 2 * q], lds[L_XIN + 2 * q + 1]);
        }
        __syncthreads();

        // ---- P2: GRU0 (1536 rows, 3 passes x 512 rows, 2 thr/row) ----
        for (int g = 0; g < 3; ++g) {
            const int row = g * 512 + (tid >> 1), sub = tid & 1;
            const uint4* wx = (const uint4*)&wih0U[row * 260 + sub * 132];
            const uint4* xp = (const uint4*)&ldsU[L_HX + sub * 132];
            float ax = 0.f;
#pragma unroll 11
            for (int k4 = 0; k4 < 33; ++k4) {
                const uint4 xv = xp[k4], wv = wx[k4];
                ax = dot2(xv.x, wv.x, ax); ax = dot2(xv.y, wv.y, ax);
                ax = dot2(xv.z, wv.z, ax); ax = dot2(xv.w, wv.w, ax);
            }
            const uint4* wh = (const uint4*)&whh0U[row * 256 + sub * 128];
            const uint4* hp = (const uint4*)&ldsU[L_H0 + sub * 128];
            float ah = 0.f;
#pragma unroll 8
            for (int k4 = 0; k4 < 32; ++k4) {
                const uint4 hv = hp[k4], wv = wh[k4];
                ah = dot2(hv.x, wv.x, ah); ah = dot2(hv.y, wv.y, ah);
                ah = dot2(hv.z, wv.z, ah); ah = dot2(hv.w, wv.w, ah);
            }
            ax += __shfl_down(ax, 1, 2); ah += __shfl_down(ah, 1, 2);
            if (sub == 0) {
                lds[L_AX + row] = ax + lds[L_BIH0 + row];
                lds[L_AH + row] = ah + lds[L_BHH0 + row];
            }
        }
        __syncthreads();
        if (tid < 512) {
            const int r = tid;
            const float rg = fsig(lds[L_AX + r] + lds[L_AH + r]);
            const float z = fsig(lds[L_AX + 512 + r] + lds[L_AH + 512 + r]);
            const float n = ftanhf(lds[L_AX + 1024 + r] + rg * lds[L_AH + 1024 + r]);
            U32H u; u.u = ldsU[L_H0 + (r >> 1)];
            const float hold = (r & 1) ? (float)u.h.y : (float)u.h.x;
            const float hs = (1.f - z) * n + z * hold;
            const float hsn = __shfl_down(hs, 1, 2);
            if ((r & 1) == 0) ldsU[L_H0 + (r >> 1)] = packh2(hs, hsn);
        }
        __syncthreads();

        // ---- P3: GRU1 (x = h0new, h = h1) ----
        for (int g = 0; g < 3; ++g) {
            const int row = g * 512 + (tid >> 1), sub = tid & 1;
            const uint4* wx = (const uint4*)&wih1U[row * 256 + sub * 128];
            const uint4* xp = (const uint4*)&ldsU[L_H0 + sub * 128];
            float ax = 0.f;
#pragma unroll 8
            for (int k4 = 0; k4 < 32; ++k4) {
                const uint4 xv = xp[k4], wv = wx[k4];
                ax = dot2(xv.x, wv.x, ax); ax = dot2(xv.y, wv.y, ax);
                ax = dot2(xv.z, wv.z, ax); ax = dot2(xv.w, wv.w, ax);
            }
            const uint4* wh = (const uint4*)&whh1U[row * 256 + sub * 128];
            const uint4* hp = (const uint4*)&ldsU[L_H1 + sub * 128];
            float ah = 0.f;
#pragma unroll 8
            for (int k4 = 0; k4 < 32; ++k4) {
                const uint4 hv = hp[k4], wv = wh[k4];
                ah = dot2(hv.x, wv.x, ah); ah = dot2(hv.y, wv.y, ah);
                ah = dot2(hv.z, wv.z, ah); ah = dot2(hv.w, wv.w, ah);
            }
            ax += __shfl_down(ax, 1, 2); ah += __shfl_down(ah, 1, 2);
            if (sub == 0) {
                lds[L_AX + row] = ax + lds[L_BIH1 + row];
                lds[L_AH + row] = ah + lds[L_BHH1 + row];
            }
        }
        __syncthreads();
        if (tid < 512) {
            const int r = tid;
            const float rg = fsig(lds[L_AX + r] + lds[L_AH + r]);
            const float z = fsig(lds[L_AX + 512 + r] + lds[L_AH + 512 + r]);
            const float n = ftanhf(lds[L_AX + 1024 + r] + rg * lds[L_AH + 1024 + r]);
            U32H u; u.u = ldsU[L_H1 + (r >> 1)];
            const float hold = (r & 1) ? (float)u.h.y : (float)u.h.x;
            const float hs = (1.f - z) * n + z * hold;
            const float hsn = __shfl_down(hs, 1, 2);
            if ((r & 1) == 0) ldsU[L_H1 + (r >> 1)] = packh2(hs, hsn);
        }
        __syncthreads();

        // ---- P4: out = relu(outW.[h1new|weighted|xin]+b); xin update ----
        {
            const int f = tid >> 7, l = tid & 127;
            const float* ow = &outW[f * 1032];
            float acc = 0.f;
#pragma unroll
            for (int i = 0; i < 2; ++i) {
                const int k2 = l * 2 + i;
                U32H u; u.u = ldsU[L_H1 + k2];
                acc += ow[2 * k2] * (float)u.h.x + ow[2 * k2 + 1] * (float)u.h.y;
                U32H v; v.u = ldsU[L_HX + 4 + k2];
                acc += ow[512 + 2 * k2] * (float)v.h.x + ow[512 + 2 * k2 + 1] * (float)v.h.y;
            }
            if (l < 8) acc += ow[1024 + l] * lds[L_XIN + l];
            acc += __shfl_down(acc, 32, 64); acc += __shfl_down(acc, 16, 64);
            acc += __shfl_down(acc, 8, 64); acc += __shfl_down(acc, 4, 64);
            acc += __shfl_down(acc, 2, 64); acc += __shfl_down(acc, 1, 64);
            if ((tid & 63) == 0) lds[L_OUTR + (tid >> 6)] = acc;
        }
        __syncthreads();
        if (tid < 8) {
            const float o = fmaxf(lds[L_OUTR + 2 * tid] + lds[L_OUTR + 2 * tid + 1] +
                                  lds[L_OB + tid], 0.f);
            out[b * 256 + t * 8 + tid] = o;
            lds[L_XIN + tid] = o;
        }
        __syncthreads();
    }
}

extern "C" void kernel_launch(void* const* d_in, const int* in_sizes, int n_in,
                              void* d_out, int out_size, void* d_ws, size_t ws_size,
                              hipStream_t stream) {
    (void)in_sizes; (void)n_in; (void)out_size; (void)ws_size;
    pack_kernel<<<NBLK_P, NTHR_P, 0, stream>>>(
        (const float*)d_in[3], (const float*)d_in[6], (const float*)d_in[7],
        (const float*)d_in[10], (const float*)d_in[11], (float*)d_ws);
    encp_kernel<<<NBLK_P, NTHR_P, 0, stream>>>(
        (const float*)d_in[2], (const float*)d_in[4], (float*)d_ws);
    decoder_kernel<<<NBLK_M, NTHR_M, 0, stream>>>(
        (const float*)d_in[0], (const float*)d_in[1], (const float*)d_in[2],
        (const float*)d_in[5], (const float*)d_in[8], (const float*)d_in[9],
        (const float*)d_in[12], (const float*)d_in[13], (const float*)d_in[14],
        (const float*)d_in[15], (float*)d_out, (float*)d_ws);
}

// Round 6
// 1039.780 us; speedup vs baseline: 8.2324x; 8.2324x over previous
//
#include <hip/hip_runtime.h>

// DecoderWithAttention: B=16, T=32, F=8, S_ENC=256, H=512, L=2.
// R12 = R10 skeleton (256 blocks = 16 batches x 16 slices, distributed
// weights L2-resident) with each sync chain collapsed toward ONE MALL round
// trip (theory: R10's residual 26us/step = 4 syncs x 4 dependent legs):
//  - hidP/h0/h1 exchanges: LL 8B chunks {payload,stamp} via single
//    global_store_dwordx2 sc0 sc1; consumer poll RETURNS payload (no drain,
//    no separate reload). h0/h1: one poll per thread.
//  - attention partials: per-WAVE vmcnt drain + per-wave flag (4/producer),
//    64 flags polled in parallel, payload bulk-read pipelined sc0sc1.
//  - prologue split into pack/encp kernels (R11) -> main has no grid sync.
//  - single-buffered slots: overwrite-at-t+1 gated by intervening syncs
//    (consumption chain verified for all phases).

namespace {
constexpr int NTHR_P = 256, NBLK_P = 256;
constexpr int NTHR = 256, NBLK = 256;

// ws layout (units: float/u32). memset covers [0, 36864) = 147456 B.
constexpr int OFF_FLG     = 0;        // [16][16][16] u32 flags (16B/wave)
constexpr int OFF_HIDP_LL = 4096;     // [16][512] u64 LL chunks
constexpr int OFF_H0LL    = 20480;    // [16][16][16] u64
constexpr int OFF_H1LL    = 28672;    // [16][16][16] u64
constexpr int OFF_ATTP    = 36864;    // [16][16][514] u32 payload (no memset)
constexpr int OFF_AEH     = 168448;   // [512][256] u32 attn_W[:,512:]
constexpr int OFF_WHID    = OFF_AEH + 131072;
constexpr int OFF_WIH0    = OFF_WHID + 131072;   // [1536][260] u32
constexpr int OFF_WHH0    = OFF_WIH0 + 399360;   // [1536][256] u32
constexpr int OFF_WIH1    = OFF_WHH0 + 393216;
constexpr int OFF_WHH1    = OFF_WIH1 + 393216;
constexpr int OFF_ENCP    = OFF_WHH1 + 393216;   // [4096][256] u32
// end = 3,058,176 floats = 12.23 MB

// main-kernel LDS
constexpr int L_H1   = 0;      // [256] u32
constexpr int L_H0   = 256;    // [256] u32
constexpr int L_HIDP = 512;    // [512] f32
constexpr int L_ES   = 1024;   // [16]
constexpr int L_HX   = 1040;   // [264] u32: xin(4)|weighted(256)|pad(4)
constexpr int L_AX   = 1304;   // [96]
constexpr int L_AH   = 1400;   // [96]
constexpr int L_HS   = 1496;   // [32]
constexpr int L_BIH0 = 1528, L_BHH0 = 1624, L_BIH1 = 1720, L_BHH1 = 1816;  // [96]
constexpr int L_VW   = 1912;   // [512]
constexpr int L_XIN  = 2424;   // [8]
constexpr int LDS_FLOATS = 2432;
}  // namespace

typedef _Float16 h2 __attribute__((ext_vector_type(2)));
union U32H { unsigned u; h2 h; };

__device__ __forceinline__ float dot2(unsigned a, unsigned b, float acc) {
    U32H ua, ub; ua.u = a; ub.u = b;
#if __has_builtin(__builtin_amdgcn_fdot2)
    return __builtin_amdgcn_fdot2(ua.h, ub.h, acc, false);
#else
    return acc + (float)ua.h.x * (float)ub.h.x + (float)ua.h.y * (float)ub.h.y;
#endif
}
__device__ __forceinline__ unsigned packh2(float a, float b) {
    U32H u; u.h = h2{(_Float16)a, (_Float16)b}; return u.u;
}
__device__ __forceinline__ float fsig(float x) { return 1.0f / (1.0f + __expf(-x)); }
__device__ __forceinline__ float ftanhf(float x) {
    float e = __expf(2.0f * x);
    return 1.0f - 2.0f / (e + 1.0f);
}
__device__ __forceinline__ float cload(const float* p) {
    return __hip_atomic_load(p, __ATOMIC_RELAXED, __HIP_MEMORY_SCOPE_SYSTEM);
}
__device__ __forceinline__ void cstore(float* p, float v) {
    __hip_atomic_store(p, v, __ATOMIC_RELAXED, __HIP_MEMORY_SCOPE_SYSTEM);
}
__device__ __forceinline__ unsigned ucload(const unsigned* p) {
    return __hip_atomic_load(p, __ATOMIC_RELAXED, __HIP_MEMORY_SCOPE_SYSTEM);
}

// LL 8B chunk ops: single-instruction system-scope store/load (MALL-coherent).
__device__ __forceinline__ void ll_store(unsigned long long* p, unsigned payload,
                                         unsigned stamp) {
    unsigned long long v = (unsigned long long)payload | ((unsigned long long)stamp << 32);
    asm volatile("global_store_dwordx2 %0, %1, off sc0 sc1" :: "v"(p), "v"(v) : "memory");
}
__device__ __forceinline__ unsigned long long ll_load(const unsigned long long* p) {
    unsigned long long v;
    asm volatile("global_load_dwordx2 %0, %1, off sc0 sc1\n\ts_waitcnt vmcnt(0)"
                 : "=v"(v) : "v"(p) : "memory");
    return v;
}
__device__ __forceinline__ unsigned ll_poll(const unsigned long long* p, unsigned stamp) {
    for (;;) {
        unsigned long long v = ll_load(p);
        if ((unsigned)(v >> 32) == stamp) return (unsigned)v;
        __builtin_amdgcn_s_sleep(1);
    }
}
__device__ __forceinline__ void flag_store(unsigned* p, unsigned v) {
    asm volatile("global_store_dword %0, %1, off sc0 sc1" :: "v"(p), "v"(v) : "memory");
}

// ===================== Kernel 1: f16 weight packing =====================
__global__ __launch_bounds__(NTHR_P) void pack_kernel(
    const float* __restrict__ attn_W, const float* __restrict__ Wih0,
    const float* __restrict__ Whh0, const float* __restrict__ Wih1,
    const float* __restrict__ Whh1, float* __restrict__ ws) {
    unsigned* aehU  = (unsigned*)(ws + OFF_AEH);
    unsigned* whidU = (unsigned*)(ws + OFF_WHID);
    unsigned* wih0U = (unsigned*)(ws + OFF_WIH0);
    unsigned* whh0U = (unsigned*)(ws + OFF_WHH0);
    unsigned* wih1U = (unsigned*)(ws + OFF_WIH1);
    unsigned* whh1U = (unsigned*)(ws + OFF_WHH1);
    const int gtid = blockIdx.x * NTHR_P + threadIdx.x;
    for (int i = gtid; i < 131072; i += NBLK_P * NTHR_P) {
        const int jr = i >> 8, p = i & 255;
        aehU[i]  = packh2(attn_W[jr * 1024 + 512 + 2 * p], attn_W[jr * 1024 + 513 + 2 * p]);
        whidU[i] = packh2(attn_W[jr * 1024 + 2 * p], attn_W[jr * 1024 + 1 + 2 * p]);
    }
    for (int i = gtid; i < 399360; i += NBLK_P * NTHR_P)
        wih0U[i] = packh2(Wih0[2 * i], Wih0[2 * i + 1]);
    for (int i = gtid; i < 393216; i += NBLK_P * NTHR_P) {
        whh0U[i] = packh2(Whh0[2 * i], Whh0[2 * i + 1]);
        wih1U[i] = packh2(Wih1[2 * i], Wih1[2 * i + 1]);
        whh1U[i] = packh2(Whh1[2 * i], Whh1[2 * i + 1]);
    }
}

// ===================== Kernel 2: enc_proj =====================
__global__ __launch_bounds__(NTHR_P) void encp_kernel(
    const float* __restrict__ enc, const float* __restrict__ attn_b,
    float* __restrict__ ws) {
    const int tid = threadIdx.x, bid = blockIdx.x;
    const int b = bid >> 4, s = bid & 15;
    const unsigned* aehU = (const unsigned*)(ws + OFF_AEH);
    unsigned* encpU = (unsigned*)(ws + OFF_ENCP);
    __shared__ __align__(16) float lds[8192];
    for (int i = 0; i < 32; ++i) {
        const int idx = tid + i * 256;
        lds[idx] = enc[(b * 256 + s * 16) * 512 + idx];  // 16 s x 512
    }
    __syncthreads();
    float a0[16], a1[16];
    const float bb0 = attn_b[2 * tid], bb1 = attn_b[2 * tid + 1];
#pragma unroll
    for (int sl = 0; sl < 16; ++sl) { a0[sl] = bb0; a1[sl] = bb1; }
    const unsigned* w0 = &aehU[(2 * tid) * 256];
    const unsigned* w1 = &aehU[(2 * tid + 1) * 256];
    for (int p = 0; p < 256; ++p) {
        const unsigned ww0 = w0[p], ww1 = w1[p];
#pragma unroll
        for (int sl = 0; sl < 16; ++sl) {
            const unsigned epk = packh2(lds[sl * 512 + 2 * p], lds[sl * 512 + 2 * p + 1]);
            a0[sl] = dot2(epk, ww0, a0[sl]);
            a1[sl] = dot2(epk, ww1, a1[sl]);
        }
    }
    for (int sl = 0; sl < 16; ++sl)
        encpU[(b * 256 + s * 16 + sl) * 256 + tid] = packh2(a0[sl], a1[sl]);
}

// ===================== Main kernel =====================
__global__ __launch_bounds__(NTHR) void decoder_kernel(
    const float* __restrict__ target, const float* __restrict__ hidden0,
    const float* __restrict__ enc, const float* __restrict__ v_w,
    const float* __restrict__ bih0, const float* __restrict__ bhh0,
    const float* __restrict__ bih1, const float* __restrict__ bhh1,
    const float* __restrict__ outW, const float* __restrict__ outBias,
    float* __restrict__ out, float* __restrict__ ws) {
    const int tid = threadIdx.x, bid = blockIdx.x;
    const int b = bid >> 4, s = bid & 15;

    unsigned* flg = (unsigned*)ws + OFF_FLG;
    unsigned long long* hidpLL = (unsigned long long*)(ws + OFF_HIDP_LL);
    unsigned long long* h0LL = (unsigned long long*)(ws + OFF_H0LL);
    unsigned long long* h1LL = (unsigned long long*)(ws + OFF_H1LL);
    float* attP = ws + OFF_ATTP;
    const unsigned* whidU = (const unsigned*)(ws + OFF_WHID);
    const unsigned* wih0U = (const unsigned*)(ws + OFF_WIH0);
    const unsigned* whh0U = (const unsigned*)(ws + OFF_WHH0);
    const unsigned* wih1U = (const unsigned*)(ws + OFF_WIH1);
    const unsigned* whh1U = (const unsigned*)(ws + OFF_WHH1);
    const unsigned* encpU = (const unsigned*)(ws + OFF_ENCP);

    __shared__ __align__(16) float lds[LDS_FLOATS];
    unsigned* ldsU = (unsigned*)lds;

    // ---- init: biases (own rows), v_w, h0/h1 full, xin, pad ----
    if (tid < 96) {
        const int grow = (tid >> 5) * 512 + s * 32 + (tid & 31);
        lds[L_BIH0 + tid] = bih0[grow]; lds[L_BHH0 + tid] = bhh0[grow];
        lds[L_BIH1 + tid] = bih1[grow]; lds[L_BHH1 + tid] = bhh1[grow];
    }
    lds[L_VW + tid] = v_w[tid];
    lds[L_VW + 256 + tid] = v_w[256 + tid];
    ldsU[L_H0 + tid] = packh2(hidden0[b * 512 + 2 * tid], hidden0[b * 512 + 2 * tid + 1]);
    ldsU[L_H1 + tid] = packh2(hidden0[8192 + b * 512 + 2 * tid],
                              hidden0[8192 + b * 512 + 2 * tid + 1]);
    if (tid < 8) lds[L_XIN + tid] = target[b * 256 + tid];
    if (tid < 4) ldsU[L_HX + 260 + tid] = 0u;  // permanent zero tail pad
    __syncthreads();

    for (int t = 0; t < 32; ++t) {
        const unsigned tgt = (unsigned)(t + 1);

        // ---- P0: hidP own rows [s*32,+32) -> LL chunks ----
        {
            const int r = tid >> 3, sub = tid & 7;
            const uint4* wrow = (const uint4*)&whidU[(s * 32 + r) * 256 + sub * 32];
            const uint4* h1p = (const uint4*)&ldsU[L_H1 + sub * 32];
            float acc = 0.f;
#pragma unroll
            for (int k4 = 0; k4 < 8; ++k4) {
                const uint4 hv = h1p[k4], wv = wrow[k4];
                acc = dot2(hv.x, wv.x, acc); acc = dot2(hv.y, wv.y, acc);
                acc = dot2(hv.z, wv.z, acc); acc = dot2(hv.w, wv.w, acc);
            }
            acc += __shfl_down(acc, 4, 8); acc += __shfl_down(acc, 2, 8); acc += __shfl_down(acc, 1, 8);
            if (sub == 0) ll_store(&hidpLL[b * 512 + s * 32 + r], __float_as_uint(acc), tgt);
        }
        // ---- P1: gather hidP (2 polls/thread) ----
        lds[L_HIDP + tid] = __uint_as_float(ll_poll(&hidpLL[b * 512 + tid], tgt));
        lds[L_HIDP + 256 + tid] = __uint_as_float(ll_poll(&hidpLL[b * 512 + 256 + tid], tgt));
        __syncthreads();

        // ---- P2: energy own 16 s-rows + exp + wp payload + per-wave flag ----
        {
            const int sloc = tid >> 4, sub = tid & 15;
            const unsigned* ep = &encpU[(b * 256 + s * 16 + sloc) * 256];
            float acc = 0.f;
#pragma unroll 4
            for (int k2 = 0; k2 < 16; ++k2) {
                const int p = k2 * 16 + sub;
                U32H u; u.u = ep[p];
                acc += lds[L_VW + 2 * p] * ftanhf((float)u.h.x + lds[L_HIDP + 2 * p]);
                acc += lds[L_VW + 2 * p + 1] * ftanhf((float)u.h.y + lds[L_HIDP + 2 * p + 1]);
            }
            acc += __shfl_down(acc, 8, 16); acc += __shfl_down(acc, 4, 16);
            acc += __shfl_down(acc, 2, 16); acc += __shfl_down(acc, 1, 16);
            if (sub == 0) lds[L_ES + sloc] = __expf(acc);  // |score|<=~20: fp32-safe
        }
        __syncthreads();
        {
            float wp0 = 0.f, wp1 = 0.f;
            const float2* er = (const float2*)&enc[(b * 256 + s * 16) * 512];
#pragma unroll
            for (int sl = 0; sl < 16; ++sl) {
                const float2 e = er[sl * 256 + tid];
                const float es = lds[L_ES + sl];
                wp0 += es * e.x; wp1 += es * e.y;
            }
            cstore(&attP[(b * 16 + s) * 514 + 2 * tid], wp0);
            cstore(&attP[(b * 16 + s) * 514 + 2 * tid + 1], wp1);
            if (tid == 0) {
                float l = 0.f;
#pragma unroll
                for (int i = 0; i < 16; ++i) l += lds[L_ES + i];
                cstore(&attP[(b * 16 + s) * 514 + 512], l);
            }
        }
        asm volatile("s_waitcnt vmcnt(0)" ::: "memory");  // per-wave payload drain
        if ((tid & 63) == 0)
            flag_store(&flg[(b * 16 + s) * 16 + (tid >> 6) * 4], tgt);

        // ---- P3: gather attention (64 parallel flag polls + pipelined bulk) --
        if (tid < 64) {
            const unsigned* fp = &flg[(b * 16 + (tid >> 2)) * 16 + (tid & 3) * 4];
            while (ucload(fp) < tgt) __builtin_amdgcn_s_sleep(1);
        }
        __syncthreads();
        __builtin_amdgcn_fence(__ATOMIC_ACQUIRE, "workgroup");
        {
            float w0 = 0.f, w1 = 0.f;
            for (int sp = 0; sp < 16; ++sp) {
                w0 += cload(&attP[(b * 16 + sp) * 514 + 2 * tid]);
                w1 += cload(&attP[(b * 16 + sp) * 514 + 2 * tid + 1]);
            }
            if (tid < 16) lds[L_ES + tid] = cload(&attP[(b * 16 + tid) * 514 + 512]);
            __syncthreads();
            float L = 0.f;
#pragma unroll
            for (int i = 0; i < 16; ++i) L += lds[L_ES + i];
            const float inv = 1.f / L;
            ldsU[L_HX + 4 + tid] = packh2(w0 * inv, w1 * inv);
            if (tid < 4) {
                ldsU[L_HX + tid] = packh2(lds[L_XIN + 2 * tid], lds[L_XIN + 2 * tid + 1]);
            }
        }
        __syncthreads();

        // ---- P4: GRU0 own 96 gate rows -> h0 slice LL ----
        if (tid < 192) {
            const int u = tid >> 1, sub = tid & 1;
            const int gh = u >> 5, r = u & 31;
            const int grow = gh * 512 + s * 32 + r;
            const uint4* wx = (const uint4*)&wih0U[grow * 260 + sub * 132];
            const uint4* xp = (const uint4*)&ldsU[L_HX + sub * 132];
            float ax = 0.f;
#pragma unroll 11
            for (int k4 = 0; k4 < 33; ++k4) {
                const uint4 xv = xp[k4], wv = wx[k4];
                ax = dot2(xv.x, wv.x, ax); ax = dot2(xv.y, wv.y, ax);
                ax = dot2(xv.z, wv.z, ax); ax = dot2(xv.w, wv.w, ax);
            }
            const uint4* wh = (const uint4*)&whh0U[grow * 256 + sub * 128];
            const uint4* hp = (const uint4*)&ldsU[L_H0 + sub * 128];
            float ah = 0.f;
#pragma unroll 8
            for (int k4 = 0; k4 < 32; ++k4) {
                const uint4 hv = hp[k4], wv = wh[k4];
                ah = dot2(hv.x, wv.x, ah); ah = dot2(hv.y, wv.y, ah);
                ah = dot2(hv.z, wv.z, ah); ah = dot2(hv.w, wv.w, ah);
            }
            ax += __shfl_down(ax, 1, 2); ah += __shfl_down(ah, 1, 2);
            if (sub == 0) {
                lds[L_AX + u] = ax + lds[L_BIH0 + u];
                lds[L_AH + u] = ah + lds[L_BHH0 + u];
            }
        }
        __syncthreads();
        if (tid < 32) {
            const int r = tid;
            const float rg = fsig(lds[L_AX + r] + lds[L_AH + r]);
            const float z = fsig(lds[L_AX + 32 + r] + lds[L_AH + 32 + r]);
            const float n = ftanhf(lds[L_AX + 64 + r] + rg * lds[L_AH + 64 + r]);
            U32H u; u.u = ldsU[L_H0 + s * 16 + (r >> 1)];
            const float hold = (r & 1) ? (float)u.h.y : (float)u.h.x;
            lds[L_HS + r] = (1.f - z) * n + z * hold;
        }
        __syncthreads();
        if (tid < 16)
            ll_store(&h0LL[(b * 16 + s) * 16 + tid],
                     packh2(lds[L_HS + 2 * tid], lds[L_HS + 2 * tid + 1]), tgt);
        // ---- P5: gather h0 (1 poll/thread) ----
        {
            const int sp = tid >> 4, jj = tid & 15;
            ldsU[L_H0 + sp * 16 + jj] = ll_poll(&h0LL[(b * 16 + sp) * 16 + jj], tgt);
        }
        __syncthreads();

        // ---- P6: GRU1 own 96 gate rows -> h1 slice LL ----
        if (tid < 192) {
            const int u = tid >> 1, sub = tid & 1;
            const int gh = u >> 5, r = u & 31;
            const int grow = gh * 512 + s * 32 + r;
            const uint4* wx = (const uint4*)&wih1U[grow * 256 + sub * 128];
            const uint4* xp = (const uint4*)&ldsU[L_H0 + sub * 128];
            float ax = 0.f;
#pragma unroll 8
            for (int k4 = 0; k4 < 32; ++k4) {
                const uint4 xv = xp[k4], wv = wx[k4];
                ax = dot2(xv.x, wv.x, ax); ax = dot2(xv.y, wv.y, ax);
                ax = dot2(xv.z, wv.z, ax); ax = dot2(xv.w, wv.w, ax);
            }
            const uint4* wh = (const uint4*)&whh1U[grow * 256 + sub * 128];
            const uint4* hp = (const uint4*)&ldsU[L_H1 + sub * 128];
            float ah = 0.f;
#pragma unroll 8
            for (int k4 = 0; k4 < 32; ++k4) {
                const uint4 hv = hp[k4], wv = wh[k4];
                ah = dot2(hv.x, wv.x, ah); ah = dot2(hv.y, wv.y, ah);
                ah = dot2(hv.z, wv.z, ah); ah = dot2(hv.w, wv.w, ah);
            }
            ax += __shfl_down(ax, 1, 2); ah += __shfl_down(ah, 1, 2);
            if (sub == 0) {
                lds[L_AX + u] = ax + lds[L_BIH1 + u];
                lds[L_AH + u] = ah + lds[L_BHH1 + u];
            }
        }
        __syncthreads();
        if (tid < 32) {
            const int r = tid;
            const float rg = fsig(lds[L_AX + r] + lds[L_AH + r]);
            const float z = fsig(lds[L_AX + 32 + r] + lds[L_AH + 32 + r]);
            const float n = ftanhf(lds[L_AX + 64 + r] + rg * lds[L_AH + 64 + r]);
            U32H u; u.u = ldsU[L_H1 + s * 16 + (r >> 1)];
            const float hold = (r & 1) ? (float)u.h.y : (float)u.h.x;
            lds[L_HS + r] = (1.f - z) * n + z * hold;
        }
        __syncthreads();
        if (tid < 16)
            ll_store(&h1LL[(b * 16 + s) * 16 + tid],
                     packh2(lds[L_HS + 2 * tid], lds[L_HS + 2 * tid + 1]), tgt);
        // ---- P7: gather h1 (1 poll/thread) ----
        {
            const int sp = tid >> 4, jj = tid & 15;
            ldsU[L_H1 + sp * 16 + jj] = ll_poll(&h1LL[(b * 16 + sp) * 16 + jj], tgt);
        }
        __syncthreads();

        // ---- P8 (local): out = relu(outW.[h1new|weighted|xin]+b); xin ----
        {
            const int f = tid >> 5, l = tid & 31;
            const float* ow = &outW[f * 1032];
            float acc = 0.f;
#pragma unroll
            for (int i = 0; i < 8; ++i) {
                const int k2 = i * 32 + l;
                U32H u; u.u = ldsU[L_H1 + k2];
                acc += ow[2 * k2] * (float)u.h.x + ow[2 * k2 + 1] * (float)u.h.y;
            }
#pragma unroll
            for (int i = 0; i < 8; ++i) {
                const int k2 = i * 32 + l;
                U32H u; u.u = ldsU[L_HX + 4 + k2];
                acc += ow[512 + 2 * k2] * (float)u.h.x + ow[512 + 2 * k2 + 1] * (float)u.h.y;
            }
            if (l < 8) acc += ow[1024 + l] * lds[L_XIN + l];
            acc += __shfl_down(acc, 16, 32); acc += __shfl_down(acc, 8, 32);
            acc += __shfl_down(acc, 4, 32); acc += __shfl_down(acc, 2, 32);
            acc += __shfl_down(acc, 1, 32);
            if (l == 0) {
                const float o = fmaxf(acc + outBias[f], 0.f);
                lds[L_ES + f] = o;
                if (s == 0) out[b * 256 + t * 8 + f] = o;
            }
        }
        __syncthreads();
        if (tid < 8) lds[L_XIN + tid] = lds[L_ES + tid];
        __syncthreads();
    }
}

extern "C" void kernel_launch(void* const* d_in, const int* in_sizes, int n_in,
                              void* d_out, int out_size, void* d_ws, size_t ws_size,
                              hipStream_t stream) {
    (void)in_sizes; (void)n_in; (void)out_size; (void)ws_size;
    hipMemsetAsync(d_ws, 0, 147456, stream);  // flags + LL stamp regions
    pack_kernel<<<NBLK_P, NTHR_P, 0, stream>>>(
        (const float*)d_in[3], (const float*)d_in[6], (const float*)d_in[7],
        (const float*)d_in[10], (const float*)d_in[11], (float*)d_ws);
    encp_kernel<<<NBLK_P, NTHR_P, 0, stream>>>(
        (const float*)d_in[2], (const float*)d_in[4], (float*)d_ws);
    decoder_kernel<<<NBLK, NTHR, 0, stream>>>(
        (const float*)d_in[0], (const float*)d_in[1], (const float*)d_in[2],
        (const float*)d_in[5], (const float*)d_in[8], (const float*)d_in[9],
        (const float*)d_in[12], (const float*)d_in[13], (const float*)d_in[14],
        (const float*)d_in[15], (float*)d_out, (float*)d_ws);
}